// Round 3
// baseline (322.817 us; speedup 1.0000x reference)
//
#include <hip/hip_runtime.h>

#define IN_F   128
#define OUT_F  64
#define GR     32    // rows per GEMM block

// ---------------- GEMM: out[n,o] = sum_k x[n,k]*W[o,k] + b[o] ----------------
// lane = output feature (64 lanes = 64 feats); wave = k-quarter (4 waves = k 0..128).
// W quarter lives in 32 VGPRs/lane; x rows read at wave-uniform addresses (scalar
// loads, SMEM pipe); only the 4-way k-reduction goes through LDS. R2's version was
// LDS-pipe-bound (~2B LDS read per FMA vs 85B/cyc budget).
__global__ __launch_bounds__(256) void gemm_kernel(
    const float* __restrict__ x, const float* __restrict__ W,
    const float* __restrict__ b, float* __restrict__ out, int N) {
    __shared__ float part[4][GR][OUT_F];   // 32 KB, conflict-free (o fastest)

    const int w = threadIdx.x >> 6;        // k-quarter 0..3
    const int o = threadIdx.x & 63;        // output feature
    const int row0 = blockIdx.x * GR;

    float wreg[32];
    #pragma unroll
    for (int j = 0; j < 32; j += 4) {
        float4 v = *(const float4*)&W[o * IN_F + w * 32 + j];
        wreg[j] = v.x; wreg[j + 1] = v.y; wreg[j + 2] = v.z; wreg[j + 3] = v.w;
    }

    for (int ri = 0; ri < GR; ++ri) {
        int r = row0 + ri;
        float acc = 0.f;
        if (r < N) {                       // uniform branch
            const float* xr = x + (size_t)r * IN_F + w * 32;  // wave-uniform -> s_load
            #pragma unroll
            for (int j = 0; j < 32; ++j) acc += xr[j] * wreg[j];
        }
        part[w][ri][o] = acc;
    }
    __syncthreads();

    for (int i = threadIdx.x; i < GR * OUT_F; i += 256) {
        int ri = i >> 6, oo = i & 63;
        int r = row0 + ri;
        if (r < N)
            out[(size_t)r * OUT_F + oo] =
                part[0][ri][oo] + part[1][ri][oo] + part[2][ri][oo] + part[3][ri][oo] + b[oo];
    }
}

// ---------------- CSR build ----------------
__global__ __launch_bounds__(256) void hist_kernel(const int* __restrict__ rowi,
                                                   int* __restrict__ counts, int E) {
    int e = blockIdx.x * 256 + threadIdx.x;
    if (e < E) atomicAdd(&counts[rowi[e]], 1);
}

__global__ __launch_bounds__(256) void scan1_kernel(const int* __restrict__ counts,
                                                    int* __restrict__ rowptr,
                                                    int* __restrict__ bsums, int N) {
    int tid = threadIdx.x, gid = blockIdx.x * 256 + tid;
    int lane = tid & 63, w = tid >> 6;
    int v = (gid < N) ? counts[gid] : 0;
    int sum = v;
    #pragma unroll
    for (int off = 1; off < 64; off <<= 1) {
        int tt = __shfl_up(sum, off, 64);
        if (lane >= off) sum += tt;
    }
    __shared__ int wsum[4];
    if (lane == 63) wsum[w] = sum;
    __syncthreads();
    int woff = 0;
    for (int i = 0; i < w; ++i) woff += wsum[i];
    int incl = sum + woff;
    if (gid < N) rowptr[gid] = incl - v;      // block-local exclusive
    if (tid == 255) bsums[blockIdx.x] = incl; // block total
}

__global__ __launch_bounds__(256) void scan2_kernel(int* __restrict__ bsums, int nb) {
    int tid = threadIdx.x;
    int lane = tid & 63, w = tid >> 6;
    int v = (tid < nb) ? bsums[tid] : 0;
    int sum = v;
    #pragma unroll
    for (int off = 1; off < 64; off <<= 1) {
        int tt = __shfl_up(sum, off, 64);
        if (lane >= off) sum += tt;
    }
    __shared__ int wsum[4];
    if (lane == 63) wsum[w] = sum;
    __syncthreads();
    int woff = 0;
    for (int i = 0; i < w; ++i) woff += wsum[i];
    if (tid < nb) bsums[tid] = sum + woff - v; // exclusive
}

__global__ __launch_bounds__(256) void scan3_kernel(int* __restrict__ rowptr,
                                                    const int* __restrict__ bsums,
                                                    int N, int E) {
    int gid = blockIdx.x * 256 + threadIdx.x;
    if (gid < N) rowptr[gid] += bsums[blockIdx.x];
    if (gid == 0) rowptr[N] = E;
}

// packed scatter: ONE 8B store per edge (R2 had two 4B stores -> 82MB WRITE_SIZE)
__global__ __launch_bounds__(256) void scatter_kernel(
    const int* __restrict__ rowi, const int* __restrict__ coli,
    const float* __restrict__ attr, int* __restrict__ cursor,
    int2* __restrict__ scv, int E) {
    int e = blockIdx.x * 256 + threadIdx.x;
    if (e >= E) return;
    int r = rowi[e];
    int p = atomicAdd(&cursor[r], 1);       // cursor pre-initialized to rowptr
    scv[p] = make_int2(coli[e], __float_as_int(attr[e]));
}

// ---------------- SPMM (CSR, no atomics): wave per row, lane = feature ----------------
__global__ __launch_bounds__(256) void spmm_csr_kernel(
    const int* __restrict__ rowptr, const int2* __restrict__ scv,
    const float* __restrict__ in, float* __restrict__ out, int N) {
    int wid = (blockIdx.x * 256 + threadIdx.x) >> 6;
    int lane = threadIdx.x & 63;
    if (wid >= N) return;
    wid = __builtin_amdgcn_readfirstlane(wid);  // force SGPR -> scalar loads below
    int beg = rowptr[wid], end = rowptr[wid + 1];
    float acc = 0.f;
    int e = beg;
    for (; e + 8 <= end; e += 8) {
        int2 v[8];
        #pragma unroll
        for (int i = 0; i < 8; ++i) v[i] = scv[e + i];       // uniform addr
        float xv[8];
        #pragma unroll
        for (int i = 0; i < 8; ++i) xv[i] = in[(size_t)v[i].x * OUT_F + lane];  // 8 gathers in flight
        #pragma unroll
        for (int i = 0; i < 8; ++i) acc += __int_as_float(v[i].y) * xv[i];
    }
    for (; e < end; ++e) {
        int2 v = scv[e];
        acc += __int_as_float(v.y) * in[(size_t)v.x * OUT_F + lane];
    }
    out[(size_t)wid * OUT_F + lane] = acc;
}

// ---------------- fallback SPMM (atomics) if ws too small ----------------
__global__ __launch_bounds__(256) void spmm_atomic_kernel(
    const int* __restrict__ rowi, const int* __restrict__ coli,
    const float* __restrict__ attr, const float* __restrict__ in,
    float* __restrict__ out, int E) {
    int tid = blockIdx.x * 256 + threadIdx.x;
    int e = tid >> 6;
    int lane = tid & 63;
    if (e >= E) return;
    int r = rowi[e];
    int c = coli[e];
    float w = attr[e];
    float v = in[(size_t)c * OUT_F + lane];
    atomicAdd(&out[(size_t)r * OUT_F + lane], w * v);
}

extern "C" void kernel_launch(void* const* d_in, const int* in_sizes, int n_in,
                              void* d_out, int out_size, void* d_ws, size_t ws_size,
                              hipStream_t stream) {
    const float* x    = (const float*)d_in[0];
    const int*   ei   = (const int*)d_in[1];    // [2, E] int32 (confirmed R1)
    const float* attr = (const float*)d_in[2];
    const float* W    = (const float*)d_in[3];
    const float* b    = (const float*)d_in[4];
    float* out = (float*)d_out;

    const int N = in_sizes[0] / IN_F;   // 50000
    const int E = in_sizes[2];          // 800000
    const int* rowi = ei;
    const int* coli = ei + E;

    const size_t obytes = (size_t)N * OUT_F * sizeof(float);

    // ---- ws layout ----
    char* wp = (char*)d_ws;
    size_t off = 0;
    auto alloc = [&](size_t bytes) { char* p = wp + off; off += (bytes + 255) & ~(size_t)255; return p; };
    float* ws0    = (float*)alloc(obytes);                    // ping-pong buffer
    int*   rowptr = (int*)  alloc((size_t)(N + 1) * 4);
    int*   counts = (int*)  alloc((size_t)N * 4);
    int*   cursor = (int*)  alloc((size_t)N * 4);
    int*   bsums  = (int*)  alloc(256 * 4);
    int2*  scv    = (int2*) alloc((size_t)E * 8);
    const bool csr_ok = (off <= ws_size);

    const int gemm_blocks = (N + GR - 1) / GR;
    const int eb = (E + 255) / 256;
    const int nb = (N + 255) / 256;              // 196 <= 256 for scan2

    // out0 = x @ W^T + b  -> ws0
    gemm_kernel<<<gemm_blocks, 256, 0, stream>>>(x, W, b, ws0, N);

    if (csr_ok) {
        // ---- build CSR (row-sorted, packed) ----
        hipMemsetAsync(counts, 0, (size_t)N * 4, stream);
        hist_kernel<<<eb, 256, 0, stream>>>(rowi, counts, E);
        scan1_kernel<<<nb, 256, 0, stream>>>(counts, rowptr, bsums, N);
        scan2_kernel<<<1, 256, 0, stream>>>(bsums, nb);
        scan3_kernel<<<nb, 256, 0, stream>>>(rowptr, bsums, N, E);
        hipMemcpyAsync(cursor, rowptr, (size_t)N * 4, hipMemcpyDeviceToDevice, stream);
        scatter_kernel<<<eb, 256, 0, stream>>>(rowi, coli, attr, cursor, scv, E);

        // ---- 3 rounds, no atomics, every row written ----
        const int sb = (N * 64 + 255) / 256;
        spmm_csr_kernel<<<sb, 256, 0, stream>>>(rowptr, scv, ws0, out, N);
        spmm_csr_kernel<<<sb, 256, 0, stream>>>(rowptr, scv, out, ws0, N);
        spmm_csr_kernel<<<sb, 256, 0, stream>>>(rowptr, scv, ws0, out, N);
    } else {
        // fallback: edge-parallel atomic path
        const int spmm_blocks = (E * 64 + 255) / 256;
        hipMemsetAsync(out, 0, obytes, stream);
        spmm_atomic_kernel<<<spmm_blocks, 256, 0, stream>>>(rowi, coli, attr, ws0, out, E);
        hipMemsetAsync(ws0, 0, obytes, stream);
        spmm_atomic_kernel<<<spmm_blocks, 256, 0, stream>>>(rowi, coli, attr, out, ws0, E);
        hipMemsetAsync(out, 0, obytes, stream);
        spmm_atomic_kernel<<<spmm_blocks, 256, 0, stream>>>(rowi, coli, attr, ws0, out, E);
    }
}

// Round 4
// 258.170 us; speedup vs baseline: 1.2504x; 1.2504x over previous
//
#include <hip/hip_runtime.h>

#define IN_F   128
#define OUT_F  64
#define GR     64    // rows per GEMM block

// ---- bf16 helpers (RNE) ----
__device__ __forceinline__ unsigned short f2bf(float f) {
    unsigned int u = __float_as_uint(f);
    u += 0x7fffu + ((u >> 16) & 1u);
    return (unsigned short)(u >> 16);
}
__device__ __forceinline__ float bf2f(unsigned short h) {
    return __uint_as_float(((unsigned int)h) << 16);
}

// ---------------- GEMM: out[n,o] = sum_k x[n,k]*W[o,k] + b[o] ----------------
// R2 structure (64x64 tile, thread = 4x4) + explicit fmaf chains (R2's mul-add
// trees cost ~5 ops/4 MACs without fast-math; fmaf gives 1 op/MAC).
template <bool BF16OUT>
__global__ __launch_bounds__(256) void gemm_kernel(
    const float* __restrict__ x, const float* __restrict__ W,
    const float* __restrict__ b, void* __restrict__ outv, int N) {
    __shared__ float xs[GR][IN_F + 4];        // 64 x 132
    __shared__ float Wt[IN_F][OUT_F + 4];     // 128 x 68, transposed (feat fastest)

    const int t = threadIdx.x;
    const int row0 = blockIdx.x * GR;

    for (int i = t; i < OUT_F * (IN_F / 4); i += 256) {
        int o = i & 63;
        int c = i >> 6;
        float4 v = ((const float4*)W)[o * (IN_F / 4) + c];
        Wt[4 * c + 0][o] = v.x;
        Wt[4 * c + 1][o] = v.y;
        Wt[4 * c + 2][o] = v.z;
        Wt[4 * c + 3][o] = v.w;
    }
    for (int i = t; i < GR * (IN_F / 4); i += 256) {
        int r = i >> 5, c = i & 31;
        int gr = row0 + r;
        float4 v = make_float4(0.f, 0.f, 0.f, 0.f);
        if (gr < N) v = ((const float4*)x)[(size_t)gr * (IN_F / 4) + c];
        *(float4*)&xs[r][4 * c] = v;
    }
    __syncthreads();

    const int f0 = (t & 15) * 4;
    const int r0 = (t >> 4) * 4;
    float acc[4][4] = {};

    #pragma unroll 2                          // full unroll spilled in R1
    for (int k = 0; k < IN_F; k += 4) {
        float4 xv[4], wv[4];
        #pragma unroll
        for (int i = 0; i < 4; ++i) xv[i] = *(const float4*)&xs[r0 + i][k];
        #pragma unroll
        for (int j = 0; j < 4; ++j) wv[j] = *(const float4*)&Wt[k + j][f0];
        #pragma unroll
        for (int i = 0; i < 4; ++i) {
            #pragma unroll
            for (int j = 0; j < 4; ++j) {
                float wx = j == 0 ? wv[0].x : (j == 1 ? wv[0].y : (j == 2 ? wv[0].z : wv[0].w));
                float wy = j == 0 ? wv[1].x : (j == 1 ? wv[1].y : (j == 2 ? wv[1].z : wv[1].w));
                float wz = j == 0 ? wv[2].x : (j == 1 ? wv[2].y : (j == 2 ? wv[2].z : wv[2].w));
                float ww = j == 0 ? wv[3].x : (j == 1 ? wv[3].y : (j == 2 ? wv[3].z : wv[3].w));
                acc[i][j] = fmaf(xv[i].x, wx, acc[i][j]);
                acc[i][j] = fmaf(xv[i].y, wy, acc[i][j]);
                acc[i][j] = fmaf(xv[i].z, wz, acc[i][j]);
                acc[i][j] = fmaf(xv[i].w, ww, acc[i][j]);
            }
        }
    }

    float4 bv = *(const float4*)&b[f0];
    #pragma unroll
    for (int i = 0; i < 4; ++i) {
        int gr = row0 + r0 + i;
        if (gr < N) {
            float o0 = acc[i][0] + bv.x, o1 = acc[i][1] + bv.y;
            float o2 = acc[i][2] + bv.z, o3 = acc[i][3] + bv.w;
            if (BF16OUT) {
                ushort4 u = { f2bf(o0), f2bf(o1), f2bf(o2), f2bf(o3) };
                *(ushort4*)((unsigned short*)outv + (size_t)gr * OUT_F + f0) = u;
            } else {
                float4 o4 = make_float4(o0, o1, o2, o3);
                *(float4*)((float*)outv + (size_t)gr * OUT_F + f0) = o4;
            }
        }
    }
}

// ---------------- CSR build ----------------
__global__ __launch_bounds__(256) void hist_kernel(const int* __restrict__ rowi,
                                                   int* __restrict__ counts, int E) {
    int e = blockIdx.x * 256 + threadIdx.x;
    if (e < E) atomicAdd(&counts[rowi[e]], 1);
}

__global__ __launch_bounds__(256) void scan1_kernel(const int* __restrict__ counts,
                                                    int* __restrict__ rowptr,
                                                    int* __restrict__ bsums, int N) {
    int tid = threadIdx.x, gid = blockIdx.x * 256 + tid;
    int lane = tid & 63, w = tid >> 6;
    int v = (gid < N) ? counts[gid] : 0;
    int sum = v;
    #pragma unroll
    for (int off = 1; off < 64; off <<= 1) {
        int tt = __shfl_up(sum, off, 64);
        if (lane >= off) sum += tt;
    }
    __shared__ int wsum[4];
    if (lane == 63) wsum[w] = sum;
    __syncthreads();
    int woff = 0;
    for (int i = 0; i < w; ++i) woff += wsum[i];
    int incl = sum + woff;
    if (gid < N) rowptr[gid] = incl - v;
    if (tid == 255) bsums[blockIdx.x] = incl;
}

__global__ __launch_bounds__(256) void scan2_kernel(int* __restrict__ bsums, int nb) {
    int tid = threadIdx.x;
    int lane = tid & 63, w = tid >> 6;
    int v = (tid < nb) ? bsums[tid] : 0;
    int sum = v;
    #pragma unroll
    for (int off = 1; off < 64; off <<= 1) {
        int tt = __shfl_up(sum, off, 64);
        if (lane >= off) sum += tt;
    }
    __shared__ int wsum[4];
    if (lane == 63) wsum[w] = sum;
    __syncthreads();
    int woff = 0;
    for (int i = 0; i < w; ++i) woff += wsum[i];
    if (tid < nb) bsums[tid] = sum + woff - v;
}

__global__ __launch_bounds__(256) void scan3_kernel(int* __restrict__ rowptr,
                                                    const int* __restrict__ bsums,
                                                    int N, int E) {
    int gid = blockIdx.x * 256 + threadIdx.x;
    if (gid < N) rowptr[gid] += bsums[blockIdx.x];
    if (gid == 0) rowptr[N] = E;
}

// packed scatter: one 8B store per edge
__global__ __launch_bounds__(256) void scatter_kernel(
    const int* __restrict__ rowi, const int* __restrict__ coli,
    const float* __restrict__ attr, int* __restrict__ cursor,
    int2* __restrict__ scv, int E) {
    int e = blockIdx.x * 256 + threadIdx.x;
    if (e >= E) return;
    int r = rowi[e];
    int p = atomicAdd(&cursor[r], 1);       // cursor pre-init to rowptr
    scv[p] = make_int2(coli[e], __float_as_int(attr[e]));
}

// ---------------- SPMM (CSR): wave per row, lane = feature; bf16 gather ----------------
template <bool BF16OUT>
__global__ __launch_bounds__(256) void spmm_csr_kernel(
    const int* __restrict__ rowptr, const int2* __restrict__ scv,
    const unsigned short* __restrict__ in, void* __restrict__ outv, int N) {
    int wid = (blockIdx.x * 256 + threadIdx.x) >> 6;
    int lane = threadIdx.x & 63;
    if (wid >= N) return;
    wid = __builtin_amdgcn_readfirstlane(wid);
    int beg = rowptr[wid], end = rowptr[wid + 1];
    float acc = 0.f;
    int e = beg;
    for (; e + 16 <= end; e += 16) {        // mean degree = 16: one batch for most rows
        int2 v[16];
        #pragma unroll
        for (int i = 0; i < 16; ++i) v[i] = scv[e + i];
        float xv[16];
        #pragma unroll
        for (int i = 0; i < 16; ++i) xv[i] = bf2f(in[(size_t)v[i].x * OUT_F + lane]);
        #pragma unroll
        for (int i = 0; i < 16; ++i) acc = fmaf(__int_as_float(v[i].y), xv[i], acc);
    }
    for (; e + 4 <= end; e += 4) {
        int2 v[4];
        #pragma unroll
        for (int i = 0; i < 4; ++i) v[i] = scv[e + i];
        float xv[4];
        #pragma unroll
        for (int i = 0; i < 4; ++i) xv[i] = bf2f(in[(size_t)v[i].x * OUT_F + lane]);
        #pragma unroll
        for (int i = 0; i < 4; ++i) acc = fmaf(__int_as_float(v[i].y), xv[i], acc);
    }
    for (; e < end; ++e) {
        int2 v = scv[e];
        acc = fmaf(__int_as_float(v.y), bf2f(in[(size_t)v.x * OUT_F + lane]), acc);
    }
    if (BF16OUT)
        ((unsigned short*)outv)[(size_t)wid * OUT_F + lane] = f2bf(acc);
    else
        ((float*)outv)[(size_t)wid * OUT_F + lane] = acc;
}

// ---------------- fallback SPMM (fp32 atomics) if ws too small ----------------
__global__ __launch_bounds__(256) void spmm_atomic_kernel(
    const int* __restrict__ rowi, const int* __restrict__ coli,
    const float* __restrict__ attr, const float* __restrict__ in,
    float* __restrict__ out, int E) {
    int tid = blockIdx.x * 256 + threadIdx.x;
    int e = tid >> 6;
    int lane = tid & 63;
    if (e >= E) return;
    int r = rowi[e];
    int c = coli[e];
    float w = attr[e];
    float v = in[(size_t)c * OUT_F + lane];
    atomicAdd(&out[(size_t)r * OUT_F + lane], w * v);
}

extern "C" void kernel_launch(void* const* d_in, const int* in_sizes, int n_in,
                              void* d_out, int out_size, void* d_ws, size_t ws_size,
                              hipStream_t stream) {
    const float* x    = (const float*)d_in[0];
    const int*   ei   = (const int*)d_in[1];    // [2, E] int32 (confirmed R1)
    const float* attr = (const float*)d_in[2];
    const float* W    = (const float*)d_in[3];
    const float* b    = (const float*)d_in[4];
    float* out = (float*)d_out;

    const int N = in_sizes[0] / IN_F;   // 50000
    const int E = in_sizes[2];          // 800000
    const int* rowi = ei;
    const int* coli = ei + E;

    const size_t obytes_f  = (size_t)N * OUT_F * sizeof(float);
    const size_t obytes_bf = (size_t)N * OUT_F * sizeof(unsigned short);

    // ---- ws layout ----
    char* wp = (char*)d_ws;
    size_t off = 0;
    auto alloc = [&](size_t bytes) { char* p = wp + off; off += (bytes + 255) & ~(size_t)255; return p; };
    unsigned short* bufA = (unsigned short*)alloc(obytes_bf);   // bf16 ping
    unsigned short* bufB = (unsigned short*)alloc(obytes_bf);   // bf16 pong
    int*   rowptr = (int*)  alloc((size_t)(N + 1) * 4);
    int*   counts = (int*)  alloc((size_t)N * 4);
    int*   cursor = (int*)  alloc((size_t)N * 4);
    int*   bsums  = (int*)  alloc(256 * 4);
    int2*  scv    = (int2*) alloc((size_t)E * 8);
    const bool csr_ok = (off <= ws_size);

    const int gemm_blocks = (N + GR - 1) / GR;
    const int eb = (E + 255) / 256;
    const int nb = (N + 255) / 256;              // 196 <= 256 for scan2
    const int sb = (N * 64 + 255) / 256;

    if (csr_ok) {
        // gemm -> bf16 bufA
        gemm_kernel<true><<<gemm_blocks, 256, 0, stream>>>(x, W, b, bufA, N);

        // ---- build CSR (row-sorted, packed) ----
        hipMemsetAsync(counts, 0, (size_t)N * 4, stream);
        hist_kernel<<<eb, 256, 0, stream>>>(rowi, counts, E);
        scan1_kernel<<<nb, 256, 0, stream>>>(counts, rowptr, bsums, N);
        scan2_kernel<<<1, 256, 0, stream>>>(bsums, nb);
        scan3_kernel<<<nb, 256, 0, stream>>>(rowptr, bsums, N, E);
        hipMemcpyAsync(cursor, rowptr, (size_t)N * 4, hipMemcpyDeviceToDevice, stream);
        scatter_kernel<<<eb, 256, 0, stream>>>(rowi, coli, attr, cursor, scv, E);

        // ---- 3 rounds: bf16 -> bf16 -> bf16 -> fp32(d_out) ----
        spmm_csr_kernel<true ><<<sb, 256, 0, stream>>>(rowptr, scv, bufA, bufB, N);
        spmm_csr_kernel<true ><<<sb, 256, 0, stream>>>(rowptr, scv, bufB, bufA, N);
        spmm_csr_kernel<false><<<sb, 256, 0, stream>>>(rowptr, scv, bufA, out, N);
    } else {
        // fallback: fp32 edge-parallel atomics, needs only one fp32 buffer
        float* ws0 = (float*)d_ws;
        gemm_kernel<false><<<gemm_blocks, 256, 0, stream>>>(x, W, b, ws0, N);
        const int spmm_blocks = (E * 64 + 255) / 256;
        hipMemsetAsync(out, 0, obytes_f, stream);
        spmm_atomic_kernel<<<spmm_blocks, 256, 0, stream>>>(rowi, coli, attr, ws0, out, E);
        hipMemsetAsync(ws0, 0, obytes_f, stream);
        spmm_atomic_kernel<<<spmm_blocks, 256, 0, stream>>>(rowi, coli, attr, out, ws0, E);
        hipMemsetAsync(out, 0, obytes_f, stream);
        spmm_atomic_kernel<<<spmm_blocks, 256, 0, stream>>>(rowi, coli, attr, ws0, out, E);
    }
}

// Round 5
// 255.480 us; speedup vs baseline: 1.2636x; 1.0105x over previous
//
#include <hip/hip_runtime.h>

#define IN_F   128
#define OUT_F  64
#define GR     64    // rows per GEMM block

// ---- bf16 helpers (RNE) ----
__device__ __forceinline__ unsigned short f2bf(float f) {
    unsigned int u = __float_as_uint(f);
    u += 0x7fffu + ((u >> 16) & 1u);
    return (unsigned short)(u >> 16);
}
__device__ __forceinline__ float bf2f(unsigned short h) {
    return __uint_as_float(((unsigned int)h) << 16);
}

// ---------------- GEMM: out[n,o] = sum_k x[n,k]*W[o,k] + b[o] ----------------
template <bool BF16OUT>
__global__ __launch_bounds__(256) void gemm_kernel(
    const float* __restrict__ x, const float* __restrict__ W,
    const float* __restrict__ b, void* __restrict__ outv, int N) {
    __shared__ float xs[GR][IN_F + 4];        // 64 x 132
    __shared__ float Wt[IN_F][OUT_F + 4];     // 128 x 68, transposed (feat fastest)

    const int t = threadIdx.x;
    const int row0 = blockIdx.x * GR;

    for (int i = t; i < OUT_F * (IN_F / 4); i += 256) {
        int o = i & 63;
        int c = i >> 6;
        float4 v = ((const float4*)W)[o * (IN_F / 4) + c];
        Wt[4 * c + 0][o] = v.x;
        Wt[4 * c + 1][o] = v.y;
        Wt[4 * c + 2][o] = v.z;
        Wt[4 * c + 3][o] = v.w;
    }
    for (int i = t; i < GR * (IN_F / 4); i += 256) {
        int r = i >> 5, c = i & 31;
        int gr = row0 + r;
        float4 v = make_float4(0.f, 0.f, 0.f, 0.f);
        if (gr < N) v = ((const float4*)x)[(size_t)gr * (IN_F / 4) + c];
        *(float4*)&xs[r][4 * c] = v;
    }
    __syncthreads();

    const int f0 = (t & 15) * 4;
    const int r0 = (t >> 4) * 4;
    float acc[4][4] = {};

    #pragma unroll 2                          // full unroll spilled in R1
    for (int k = 0; k < IN_F; k += 4) {
        float4 xv[4], wv[4];
        #pragma unroll
        for (int i = 0; i < 4; ++i) xv[i] = *(const float4*)&xs[r0 + i][k];
        #pragma unroll
        for (int j = 0; j < 4; ++j) wv[j] = *(const float4*)&Wt[k + j][f0];
        #pragma unroll
        for (int i = 0; i < 4; ++i) {
            #pragma unroll
            for (int j = 0; j < 4; ++j) {
                float wx = j == 0 ? wv[0].x : (j == 1 ? wv[0].y : (j == 2 ? wv[0].z : wv[0].w));
                float wy = j == 0 ? wv[1].x : (j == 1 ? wv[1].y : (j == 2 ? wv[1].z : wv[1].w));
                float wz = j == 0 ? wv[2].x : (j == 1 ? wv[2].y : (j == 2 ? wv[2].z : wv[2].w));
                float ww = j == 0 ? wv[3].x : (j == 1 ? wv[3].y : (j == 2 ? wv[3].z : wv[3].w));
                acc[i][j] = fmaf(xv[i].x, wx, acc[i][j]);
                acc[i][j] = fmaf(xv[i].y, wy, acc[i][j]);
                acc[i][j] = fmaf(xv[i].z, wz, acc[i][j]);
                acc[i][j] = fmaf(xv[i].w, ww, acc[i][j]);
            }
        }
    }

    float4 bv = *(const float4*)&b[f0];
    #pragma unroll
    for (int i = 0; i < 4; ++i) {
        int gr = row0 + r0 + i;
        if (gr < N) {
            float o0 = acc[i][0] + bv.x, o1 = acc[i][1] + bv.y;
            float o2 = acc[i][2] + bv.z, o3 = acc[i][3] + bv.w;
            if (BF16OUT) {
                ushort4 u = { f2bf(o0), f2bf(o1), f2bf(o2), f2bf(o3) };
                *(ushort4*)((unsigned short*)outv + (size_t)gr * OUT_F + f0) = u;
            } else {
                float4 o4 = make_float4(o0, o1, o2, o3);
                *(float4*)((float*)outv + (size_t)gr * OUT_F + f0) = o4;
            }
        }
    }
}

// ---------------- CSR build ----------------
__global__ __launch_bounds__(256) void hist_kernel(const int* __restrict__ rowi,
                                                   int* __restrict__ counts, int E) {
    int e = blockIdx.x * 256 + threadIdx.x;
    if (e < E) atomicAdd(&counts[rowi[e]], 1);
}

__global__ __launch_bounds__(256) void scan1_kernel(const int* __restrict__ counts,
                                                    int* __restrict__ rowptr,
                                                    int* __restrict__ bsums, int N) {
    int tid = threadIdx.x, gid = blockIdx.x * 256 + tid;
    int lane = tid & 63, w = tid >> 6;
    int v = (gid < N) ? counts[gid] : 0;
    int sum = v;
    #pragma unroll
    for (int off = 1; off < 64; off <<= 1) {
        int tt = __shfl_up(sum, off, 64);
        if (lane >= off) sum += tt;
    }
    __shared__ int wsum[4];
    if (lane == 63) wsum[w] = sum;
    __syncthreads();
    int woff = 0;
    for (int i = 0; i < w; ++i) woff += wsum[i];
    int incl = sum + woff;
    if (gid < N) rowptr[gid] = incl - v;
    if (tid == 255) bsums[blockIdx.x] = incl;
}

__global__ __launch_bounds__(256) void scan2_kernel(int* __restrict__ bsums, int nb) {
    int tid = threadIdx.x;
    int lane = tid & 63, w = tid >> 6;
    int v = (tid < nb) ? bsums[tid] : 0;
    int sum = v;
    #pragma unroll
    for (int off = 1; off < 64; off <<= 1) {
        int tt = __shfl_up(sum, off, 64);
        if (lane >= off) sum += tt;
    }
    __shared__ int wsum[4];
    if (lane == 63) wsum[w] = sum;
    __syncthreads();
    int woff = 0;
    for (int i = 0; i < w; ++i) woff += wsum[i];
    if (tid < nb) bsums[tid] = sum + woff - v;
}

__global__ __launch_bounds__(256) void scan3_kernel(int* __restrict__ rowptr,
                                                    const int* __restrict__ bsums,
                                                    int N, int E) {
    int gid = blockIdx.x * 256 + threadIdx.x;
    if (gid < N) rowptr[gid] += bsums[blockIdx.x];
    if (gid == 0) rowptr[N] = E;
}

// packed scatter: ONE 4B store per edge — {u16 col | bf16 val}.
// R4's 8B records hit the 64B-sector writeback floor (52MB for 6.4MB payload);
// 4B records halve the region and the per-sector XCD bounce.
__global__ __launch_bounds__(256) void scatter_kernel(
    const int* __restrict__ rowi, const int* __restrict__ coli,
    const float* __restrict__ attr, int* __restrict__ cursor,
    unsigned int* __restrict__ scv, int E) {
    int e = blockIdx.x * 256 + threadIdx.x;
    if (e >= E) return;
    int r = rowi[e];
    int p = atomicAdd(&cursor[r], 1);       // cursor pre-init to rowptr
    unsigned int rec = ((unsigned int)coli[e] << 16) | (unsigned int)f2bf(attr[e]);
    scv[p] = rec;
}

// ---------------- SPMM (CSR): wave per row, lane = feature; bf16 gather ----------------
template <bool BF16OUT>
__global__ __launch_bounds__(256) void spmm_csr_kernel(
    const int* __restrict__ rowptr, const unsigned int* __restrict__ scv,
    const unsigned short* __restrict__ in, void* __restrict__ outv, int N) {
    int wid = (blockIdx.x * 256 + threadIdx.x) >> 6;
    int lane = threadIdx.x & 63;
    if (wid >= N) return;
    wid = __builtin_amdgcn_readfirstlane(wid);
    int beg = rowptr[wid], end = rowptr[wid + 1];
    float acc = 0.f;
    int e = beg;
    for (; e + 16 <= end; e += 16) {        // mean degree = 16
        unsigned int v[16];
        #pragma unroll
        for (int i = 0; i < 16; ++i) v[i] = scv[e + i];
        float xv[16];
        #pragma unroll
        for (int i = 0; i < 16; ++i) xv[i] = bf2f(in[(size_t)(v[i] >> 16) * OUT_F + lane]);
        #pragma unroll
        for (int i = 0; i < 16; ++i) acc = fmaf(bf2f((unsigned short)(v[i] & 0xffffu)), xv[i], acc);
    }
    for (; e + 4 <= end; e += 4) {
        unsigned int v[4];
        #pragma unroll
        for (int i = 0; i < 4; ++i) v[i] = scv[e + i];
        float xv[4];
        #pragma unroll
        for (int i = 0; i < 4; ++i) xv[i] = bf2f(in[(size_t)(v[i] >> 16) * OUT_F + lane]);
        #pragma unroll
        for (int i = 0; i < 4; ++i) acc = fmaf(bf2f((unsigned short)(v[i] & 0xffffu)), xv[i], acc);
    }
    for (; e < end; ++e) {
        unsigned int v = scv[e];
        acc = fmaf(bf2f((unsigned short)(v & 0xffffu)),
                   bf2f(in[(size_t)(v >> 16) * OUT_F + lane]), acc);
    }
    if (BF16OUT)
        ((unsigned short*)outv)[(size_t)wid * OUT_F + lane] = f2bf(acc);
    else
        ((float*)outv)[(size_t)wid * OUT_F + lane] = acc;
}

// ---------------- fallback SPMM (fp32 atomics) if ws too small ----------------
__global__ __launch_bounds__(256) void spmm_atomic_kernel(
    const int* __restrict__ rowi, const int* __restrict__ coli,
    const float* __restrict__ attr, const float* __restrict__ in,
    float* __restrict__ out, int E) {
    int tid = blockIdx.x * 256 + threadIdx.x;
    int e = tid >> 6;
    int lane = tid & 63;
    if (e >= E) return;
    int r = rowi[e];
    int c = coli[e];
    float w = attr[e];
    float v = in[(size_t)c * OUT_F + lane];
    atomicAdd(&out[(size_t)r * OUT_F + lane], w * v);
}

extern "C" void kernel_launch(void* const* d_in, const int* in_sizes, int n_in,
                              void* d_out, int out_size, void* d_ws, size_t ws_size,
                              hipStream_t stream) {
    const float* x    = (const float*)d_in[0];
    const int*   ei   = (const int*)d_in[1];    // [2, E] int32 (confirmed R1)
    const float* attr = (const float*)d_in[2];
    const float* W    = (const float*)d_in[3];
    const float* b    = (const float*)d_in[4];
    float* out = (float*)d_out;

    const int N = in_sizes[0] / IN_F;   // 50000
    const int E = in_sizes[2];          // 800000
    const int* rowi = ei;
    const int* coli = ei + E;

    const size_t obytes_f  = (size_t)N * OUT_F * sizeof(float);
    const size_t obytes_bf = (size_t)N * OUT_F * sizeof(unsigned short);

    // ---- ws layout ----
    char* wp = (char*)d_ws;
    size_t off = 0;
    auto alloc = [&](size_t bytes) { char* p = wp + off; off += (bytes + 255) & ~(size_t)255; return p; };
    unsigned short* bufA = (unsigned short*)alloc(obytes_bf);   // bf16 ping
    unsigned short* bufB = (unsigned short*)alloc(obytes_bf);   // bf16 pong
    int*   rowptr = (int*)  alloc((size_t)(N + 1) * 4);
    int*   counts = (int*)  alloc((size_t)N * 4);
    int*   cursor = (int*)  alloc((size_t)N * 4);
    int*   bsums  = (int*)  alloc(256 * 4);
    unsigned int* scv = (unsigned int*)alloc((size_t)E * 4);
    const bool csr_ok = (off <= ws_size) && (N < 65536);

    const int gemm_blocks = (N + GR - 1) / GR;
    const int eb = (E + 255) / 256;
    const int nb = (N + 255) / 256;              // 196 <= 256 for scan2
    const int sb = (N * 64 + 255) / 256;

    if (csr_ok) {
        // gemm -> bf16 bufA
        gemm_kernel<true><<<gemm_blocks, 256, 0, stream>>>(x, W, b, bufA, N);

        // ---- build CSR (row-sorted, packed 4B records) ----
        hipMemsetAsync(counts, 0, (size_t)N * 4, stream);
        hist_kernel<<<eb, 256, 0, stream>>>(rowi, counts, E);
        scan1_kernel<<<nb, 256, 0, stream>>>(counts, rowptr, bsums, N);
        scan2_kernel<<<1, 256, 0, stream>>>(bsums, nb);
        scan3_kernel<<<nb, 256, 0, stream>>>(rowptr, bsums, N, E);
        hipMemcpyAsync(cursor, rowptr, (size_t)N * 4, hipMemcpyDeviceToDevice, stream);
        scatter_kernel<<<eb, 256, 0, stream>>>(rowi, coli, attr, cursor, scv, E);

        // ---- 3 rounds: bf16 -> bf16 -> bf16 -> fp32(d_out) ----
        spmm_csr_kernel<true ><<<sb, 256, 0, stream>>>(rowptr, scv, bufA, bufB, N);
        spmm_csr_kernel<true ><<<sb, 256, 0, stream>>>(rowptr, scv, bufB, bufA, N);
        spmm_csr_kernel<false><<<sb, 256, 0, stream>>>(rowptr, scv, bufA, out, N);
    } else {
        // fallback: fp32 edge-parallel atomics, needs only one fp32 buffer
        float* ws0 = (float*)d_ws;
        gemm_kernel<false><<<gemm_blocks, 256, 0, stream>>>(x, W, b, ws0, N);
        const int spmm_blocks = (E * 64 + 255) / 256;
        hipMemsetAsync(out, 0, obytes_f, stream);
        spmm_atomic_kernel<<<spmm_blocks, 256, 0, stream>>>(rowi, coli, attr, ws0, out, E);
        hipMemsetAsync(ws0, 0, obytes_f, stream);
        spmm_atomic_kernel<<<spmm_blocks, 256, 0, stream>>>(rowi, coli, attr, out, ws0, E);
        hipMemsetAsync(out, 0, obytes_f, stream);
        spmm_atomic_kernel<<<spmm_blocks, 256, 0, stream>>>(rowi, coli, attr, ws0, out, E);
    }
}

// Round 6
// 200.964 us; speedup vs baseline: 1.6063x; 1.2713x over previous
//
#include <hip/hip_runtime.h>

#define IN_F   128
#define OUT_F  64
#define GR     64    // rows per GEMM block
#define EPB    4096  // edges per bin block

// ---- bf16 helpers (RNE) ----
__device__ __forceinline__ unsigned short f2bf(float f) {
    unsigned int u = __float_as_uint(f);
    u += 0x7fffu + ((u >> 16) & 1u);
    return (unsigned short)(u >> 16);
}
__device__ __forceinline__ float bf2f(unsigned short h) {
    return __uint_as_float(((unsigned int)h) << 16);
}

// ---------------- GEMM: out[n,o] = sum_k x[n,k]*W[o,k] + b[o] ----------------
template <bool BF16OUT>
__global__ __launch_bounds__(256) void gemm_kernel(
    const float* __restrict__ x, const float* __restrict__ W,
    const float* __restrict__ b, void* __restrict__ outv, int N) {
    __shared__ float xs[GR][IN_F + 4];
    __shared__ float Wt[IN_F][OUT_F + 4];

    const int t = threadIdx.x;
    const int row0 = blockIdx.x * GR;

    for (int i = t; i < OUT_F * (IN_F / 4); i += 256) {
        int o = i & 63;
        int c = i >> 6;
        float4 v = ((const float4*)W)[o * (IN_F / 4) + c];
        Wt[4 * c + 0][o] = v.x;
        Wt[4 * c + 1][o] = v.y;
        Wt[4 * c + 2][o] = v.z;
        Wt[4 * c + 3][o] = v.w;
    }
    for (int i = t; i < GR * (IN_F / 4); i += 256) {
        int r = i >> 5, c = i & 31;
        int gr = row0 + r;
        float4 v = make_float4(0.f, 0.f, 0.f, 0.f);
        if (gr < N) v = ((const float4*)x)[(size_t)gr * (IN_F / 4) + c];
        *(float4*)&xs[r][4 * c] = v;
    }
    __syncthreads();

    const int f0 = (t & 15) * 4;
    const int r0 = (t >> 4) * 4;
    float acc[4][4] = {};

    #pragma unroll 2
    for (int k = 0; k < IN_F; k += 4) {
        float4 xv[4], wv[4];
        #pragma unroll
        for (int i = 0; i < 4; ++i) xv[i] = *(const float4*)&xs[r0 + i][k];
        #pragma unroll
        for (int j = 0; j < 4; ++j) wv[j] = *(const float4*)&Wt[k + j][f0];
        #pragma unroll
        for (int i = 0; i < 4; ++i) {
            #pragma unroll
            for (int j = 0; j < 4; ++j) {
                float wx = j == 0 ? wv[0].x : (j == 1 ? wv[0].y : (j == 2 ? wv[0].z : wv[0].w));
                float wy = j == 0 ? wv[1].x : (j == 1 ? wv[1].y : (j == 2 ? wv[1].z : wv[1].w));
                float wz = j == 0 ? wv[2].x : (j == 1 ? wv[2].y : (j == 2 ? wv[2].z : wv[2].w));
                float ww = j == 0 ? wv[3].x : (j == 1 ? wv[3].y : (j == 2 ? wv[3].z : wv[3].w));
                acc[i][j] = fmaf(xv[i].x, wx, acc[i][j]);
                acc[i][j] = fmaf(xv[i].y, wy, acc[i][j]);
                acc[i][j] = fmaf(xv[i].z, wz, acc[i][j]);
                acc[i][j] = fmaf(xv[i].w, ww, acc[i][j]);
            }
        }
    }

    float4 bv = *(const float4*)&b[f0];
    #pragma unroll
    for (int i = 0; i < 4; ++i) {
        int gr = row0 + r0 + i;
        if (gr < N) {
            float o0 = acc[i][0] + bv.x, o1 = acc[i][1] + bv.y;
            float o2 = acc[i][2] + bv.z, o3 = acc[i][3] + bv.w;
            if (BF16OUT) {
                ushort4 u = { f2bf(o0), f2bf(o1), f2bf(o2), f2bf(o3) };
                *(ushort4*)((unsigned short*)outv + (size_t)gr * OUT_F + f0) = u;
            } else {
                float4 o4 = make_float4(o0, o1, o2, o3);
                *(float4*)((float*)outv + (size_t)gr * OUT_F + f0) = o4;
            }
        }
    }
}

// ---------------- Phase 1: bucket histogram (bucket = row >> 8), LDS-aggregated ----------------
__global__ __launch_bounds__(256) void bhist_kernel(const int* __restrict__ rowi,
                                                    int* __restrict__ bcnt, int E) {
    __shared__ int cnt[256];
    int t = threadIdx.x;
    cnt[t] = 0;
    __syncthreads();
    for (int e = blockIdx.x * 256 + t; e < E; e += gridDim.x * 256)
        atomicAdd(&cnt[rowi[e] >> 8], 1);
    __syncthreads();
    if (cnt[t] > 0) atomicAdd(&bcnt[t], cnt[t]);
}

// ---------------- Phase 2: scan bucket counts -> bases & cursors (1 block) ----------------
__global__ __launch_bounds__(256) void bscan_kernel(const int* __restrict__ bcnt,
                                                    int* __restrict__ bbase,
                                                    int* __restrict__ bcursor,
                                                    int* __restrict__ rowptr,
                                                    int nb, int N, int E) {
    int t = threadIdx.x;
    int v = (t < nb) ? bcnt[t] : 0;
    int lane = t & 63, w = t >> 6;
    int sum = v;
    #pragma unroll
    for (int off = 1; off < 64; off <<= 1) {
        int x = __shfl_up(sum, off, 64);
        if (lane >= off) sum += x;
    }
    __shared__ int wsum[4];
    if (lane == 63) wsum[w] = sum;
    __syncthreads();
    int woff = 0;
    for (int i = 0; i < w; ++i) woff += wsum[i];
    int excl = sum + woff - v;
    if (t <= nb) bbase[t] = excl;          // bbase[nb] = E
    if (t < nb)  bcursor[t] = excl;
    if (t == 0)  rowptr[N] = E;            // safety (also written by bsort when N%256 != 0)
}

// ---------------- Phase 3: bin edges into bucket segments (8B recs, chunked writes) ---------
// rec = {rowlocal:32 | col:16 | bf16val:16}; chunks reserved per (block,bucket) so
// writes land in ~21-record contiguous runs instead of 800K isolated sectors (R5 lesson).
__global__ __launch_bounds__(256) void bin_kernel(
    const int* __restrict__ rowi, const int* __restrict__ coli,
    const float* __restrict__ attr, int* __restrict__ bcursor,
    unsigned long long* __restrict__ tmp, int E) {
    __shared__ int cnt[256];
    __shared__ int cur[256];
    __shared__ int gbase[256];
    int t = threadIdx.x;
    int e0 = blockIdx.x * EPB;
    cnt[t] = 0;
    cur[t] = 0;
    __syncthreads();
    int myrow[16];
    #pragma unroll
    for (int i = 0; i < 16; ++i) {
        int e = e0 + i * 256 + t;
        myrow[i] = (e < E) ? rowi[e] : -1;
        if (myrow[i] >= 0) atomicAdd(&cnt[myrow[i] >> 8], 1);
    }
    __syncthreads();
    if (cnt[t] > 0) gbase[t] = atomicAdd(&bcursor[t], cnt[t]);
    __syncthreads();
    #pragma unroll
    for (int i = 0; i < 16; ++i) {
        int e = e0 + i * 256 + t;
        if (myrow[i] >= 0) {
            int b = myrow[i] >> 8;
            int rank = atomicAdd(&cur[b], 1);
            unsigned long long rec = ((unsigned long long)(myrow[i] & 255) << 32)
                                   | ((unsigned int)coli[e] << 16)
                                   | (unsigned int)f2bf(attr[e]);
            tmp[(size_t)gbase[b] + rank] = rec;
        }
    }
}

// ---------------- Phase 4: per-bucket sort -> scv + rowptr (all L2-window-local) ------------
__global__ __launch_bounds__(256) void bsort_kernel(
    const unsigned long long* __restrict__ tmp, const int* __restrict__ bbase,
    unsigned int* __restrict__ scv, int* __restrict__ rowptr, int N) {
    __shared__ int cnt[256];
    __shared__ int cur[256];
    __shared__ int wsum[4];
    int t = threadIdx.x, b = blockIdx.x;
    int seg = bbase[b], segend = bbase[b + 1];
    cnt[t] = 0;
    __syncthreads();
    for (int i = seg + t; i < segend; i += 256)
        atomicAdd(&cnt[(int)(tmp[i] >> 32)], 1);
    __syncthreads();
    int v = cnt[t];
    int lane = t & 63, w = t >> 6;
    int sum = v;
    #pragma unroll
    for (int off = 1; off < 64; off <<= 1) {
        int x = __shfl_up(sum, off, 64);
        if (lane >= off) sum += x;
    }
    if (lane == 63) wsum[w] = sum;
    __syncthreads();
    int woff = 0;
    for (int i = 0; i < w; ++i) woff += wsum[i];
    int excl = sum + woff - v;
    int gidx = b * 256 + t;
    if (gidx <= N) rowptr[gidx] = seg + excl;
    cur[t] = excl;
    __syncthreads();
    for (int i = seg + t; i < segend; i += 256) {
        unsigned long long rec = tmp[i];
        int rl = (int)(rec >> 32);
        int pos = atomicAdd(&cur[rl], 1);
        scv[(size_t)seg + pos] = (unsigned int)rec;   // random 4B within 16KB L2 window
    }
}

// ---------------- SPMM (CSR): wave per row, lane = feature; bf16 gather ----------------
template <bool BF16OUT>
__global__ __launch_bounds__(256) void spmm_csr_kernel(
    const int* __restrict__ rowptr, const unsigned int* __restrict__ scv,
    const unsigned short* __restrict__ in, void* __restrict__ outv, int N) {
    int wid = (blockIdx.x * 256 + threadIdx.x) >> 6;
    int lane = threadIdx.x & 63;
    if (wid >= N) return;
    wid = __builtin_amdgcn_readfirstlane(wid);
    int beg = rowptr[wid], end = rowptr[wid + 1];
    float acc = 0.f;
    int e = beg;
    for (; e + 16 <= end; e += 16) {
        unsigned int v[16];
        #pragma unroll
        for (int i = 0; i < 16; ++i) v[i] = scv[e + i];
        float xv[16];
        #pragma unroll
        for (int i = 0; i < 16; ++i) xv[i] = bf2f(in[(size_t)(v[i] >> 16) * OUT_F + lane]);
        #pragma unroll
        for (int i = 0; i < 16; ++i) acc = fmaf(bf2f((unsigned short)(v[i] & 0xffffu)), xv[i], acc);
    }
    for (; e + 4 <= end; e += 4) {
        unsigned int v[4];
        #pragma unroll
        for (int i = 0; i < 4; ++i) v[i] = scv[e + i];
        float xv[4];
        #pragma unroll
        for (int i = 0; i < 4; ++i) xv[i] = bf2f(in[(size_t)(v[i] >> 16) * OUT_F + lane]);
        #pragma unroll
        for (int i = 0; i < 4; ++i) acc = fmaf(bf2f((unsigned short)(v[i] & 0xffffu)), xv[i], acc);
    }
    for (; e < end; ++e) {
        unsigned int v = scv[e];
        acc = fmaf(bf2f((unsigned short)(v & 0xffffu)),
                   bf2f(in[(size_t)(v >> 16) * OUT_F + lane]), acc);
    }
    if (BF16OUT)
        ((unsigned short*)outv)[(size_t)wid * OUT_F + lane] = f2bf(acc);
    else
        ((float*)outv)[(size_t)wid * OUT_F + lane] = acc;
}

// ---------------- fallback SPMM (fp32 atomics) if ws too small ----------------
__global__ __launch_bounds__(256) void spmm_atomic_kernel(
    const int* __restrict__ rowi, const int* __restrict__ coli,
    const float* __restrict__ attr, const float* __restrict__ in,
    float* __restrict__ out, int E) {
    int tid = blockIdx.x * 256 + threadIdx.x;
    int e = tid >> 6;
    int lane = tid & 63;
    if (e >= E) return;
    int r = rowi[e];
    int c = coli[e];
    float w = attr[e];
    float v = in[(size_t)c * OUT_F + lane];
    atomicAdd(&out[(size_t)r * OUT_F + lane], w * v);
}

extern "C" void kernel_launch(void* const* d_in, const int* in_sizes, int n_in,
                              void* d_out, int out_size, void* d_ws, size_t ws_size,
                              hipStream_t stream) {
    const float* x    = (const float*)d_in[0];
    const int*   ei   = (const int*)d_in[1];    // [2, E] int32 (confirmed R1)
    const float* attr = (const float*)d_in[2];
    const float* W    = (const float*)d_in[3];
    const float* b    = (const float*)d_in[4];
    float* out = (float*)d_out;

    const int N = in_sizes[0] / IN_F;   // 50000
    const int E = in_sizes[2];          // 800000
    const int* rowi = ei;
    const int* coli = ei + E;

    const size_t obytes_f  = (size_t)N * OUT_F * sizeof(float);
    const size_t obytes_bf = (size_t)N * OUT_F * sizeof(unsigned short);
    const int nb = (N + 255) / 256;     // 196 buckets

    // ---- ws layout (tmp overlays bufB: tmp dead before spmm round 1 writes bufB) ----
    char* wp = (char*)d_ws;
    size_t off = 0;
    auto alloc = [&](size_t bytes) { char* p = wp + off; off += (bytes + 255) & ~(size_t)255; return p; };
    unsigned short* bufA = (unsigned short*)alloc(obytes_bf);            // bf16 ping
    unsigned short* bufB = (unsigned short*)alloc((size_t)E * 8);        // bf16 pong / tmp overlay
    unsigned long long* tmp = (unsigned long long*)bufB;
    int* rowptr  = (int*)alloc((size_t)(N + 1) * 4);
    int* bcnt    = (int*)alloc(260 * 4);
    int* bbase   = (int*)alloc(260 * 4);
    int* bcursor = (int*)alloc(260 * 4);
    unsigned int* scv = (unsigned int*)alloc((size_t)E * 4);
    const bool csr_ok = (off <= ws_size) && (N <= 65280) && ((size_t)E * 8 >= obytes_bf);

    const int gemm_blocks = (N + GR - 1) / GR;
    const int sb = (N * 64 + 255) / 256;

    if (csr_ok) {
        gemm_kernel<true><<<gemm_blocks, 256, 0, stream>>>(x, W, b, bufA, N);

        // ---- build row-sorted packed CSR via 2-phase bucketed counting sort ----
        hipMemsetAsync(bcnt, 0, 260 * 4, stream);
        bhist_kernel<<<512, 256, 0, stream>>>(rowi, bcnt, E);
        bscan_kernel<<<1, 256, 0, stream>>>(bcnt, bbase, bcursor, rowptr, nb, N, E);
        bin_kernel<<<(E + EPB - 1) / EPB, 256, 0, stream>>>(rowi, coli, attr, bcursor, tmp, E);
        bsort_kernel<<<nb, 256, 0, stream>>>(tmp, bbase, scv, rowptr, N);

        // ---- 3 rounds: bf16 -> bf16 -> bf16 -> fp32(d_out) ----
        spmm_csr_kernel<true ><<<sb, 256, 0, stream>>>(rowptr, scv, bufA, bufB, N);
        spmm_csr_kernel<true ><<<sb, 256, 0, stream>>>(rowptr, scv, bufB, bufA, N);
        spmm_csr_kernel<false><<<sb, 256, 0, stream>>>(rowptr, scv, bufA, out, N);
    } else {
        // fallback: fp32 edge-parallel atomics, needs only one fp32 buffer
        float* ws0 = (float*)d_ws;
        gemm_kernel<false><<<gemm_blocks, 256, 0, stream>>>(x, W, b, ws0, N);
        const int spmm_blocks = (E * 64 + 255) / 256;
        hipMemsetAsync(out, 0, obytes_f, stream);
        spmm_atomic_kernel<<<spmm_blocks, 256, 0, stream>>>(rowi, coli, attr, ws0, out, E);
        hipMemsetAsync(ws0, 0, obytes_f, stream);
        spmm_atomic_kernel<<<spmm_blocks, 256, 0, stream>>>(rowi, coli, attr, out, ws0, E);
        hipMemsetAsync(out, 0, obytes_f, stream);
        spmm_atomic_kernel<<<spmm_blocks, 256, 0, stream>>>(rowi, coli, attr, ws0, out, E);
    }
}